// Round 10
// baseline (135.888 us; speedup 1.0000x reference)
//
#include <hip/hip_runtime.h>
#include <hip/hip_bf16.h>
#include <stdint.h>

typedef __attribute__((ext_vector_type(8))) short short8;
typedef __attribute__((ext_vector_type(4))) float f32x4;

__device__ __forceinline__ unsigned int f2bf(float f) {
    unsigned int u = __float_as_uint(f);
    return (u + 0x7fffu + ((u >> 16) & 1u)) >> 16;   // RNE fp32 -> bf16
}

// ---- kernel 1: fp32 -> bf16 in FRAGMENT-NATIVE layout + row squared norms ----
// Element (row,k) at byte (row>>4)*4096 + (k>>3)*256 + (row&15)*16 + (k&7)*2.
// Also zeroes the accumulator and completion counter.
__global__ void prep_kernel(const float* __restrict__ emb,
                            unsigned short* __restrict__ ebs,
                            float* __restrict__ sq,
                            float* __restrict__ accum,
                            unsigned int* __restrict__ counter, int n) {
    int t = threadIdx.x;
    if (blockIdx.x == 0 && t == 0) { accum[0] = 0.0f; counter[0] = 0u; }
    int row = blockIdx.x * 16 + (t >> 4);
    int c   = t & 15;                       // k-chunk (8 elems / 16B)
    if (row >= n) return;
    const float* src = emb + (size_t)row * 128 + c * 8;
    float4 f0 = *reinterpret_cast<const float4*>(src);
    float4 f1 = *reinterpret_cast<const float4*>(src + 4);
    uint4 wv;
    wv.x = f2bf(f0.x) | (f2bf(f0.y) << 16);
    wv.y = f2bf(f0.z) | (f2bf(f0.w) << 16);
    wv.z = f2bf(f1.x) | (f2bf(f1.y) << 16);
    wv.w = f2bf(f1.z) | (f2bf(f1.w) << 16);
    size_t byte = (size_t)(row >> 4) * 4096 + c * 256 + (row & 15) * 16;
    *reinterpret_cast<uint4*>(reinterpret_cast<char*>(ebs) + byte) = wv;
    float p = f0.x*f0.x + f0.y*f0.y + f0.z*f0.z + f0.w*f0.w
            + f1.x*f1.x + f1.y*f1.y + f1.z*f1.z + f1.w*f1.w;
    #pragma unroll
    for (int off = 1; off < 16; off <<= 1) p += __shfl_xor(p, off);
    if (c == 0) sq[row] = p;
}

// ---- kernel 2: zero-LDS, zero-barrier, register-double-buffered tile stream --
// Block = (64-row band bi, chunk c of 8 col-tiles of 64). 4 waves of 32x32.
// A-fragments pinned in registers; B-tile (+sq/lab) double-buffered in regs
// with prefetch issued one full tile (MFMA+epilogue) ahead.
__launch_bounds__(256, 4)
__global__ void loss_kernel(const unsigned short* __restrict__ ebs,
                            const int* __restrict__ labels,
                            const float* __restrict__ sq,
                            float* __restrict__ accum,
                            unsigned int* __restrict__ counter,
                            float* __restrict__ out, float inv_pairs,
                            int nb, int nch, int nBlocks) {
    __shared__ float wsum[4];

    // blockIdx -> (bi, c): only chunks containing tiles jt >= bi
    int id = blockIdx.x, bi = 0, c = 0;
    for (bi = 0; bi < nb; ++bi) {
        int c0  = bi >> 3;
        int cnt = nch - c0;
        if (id < cnt) { c = c0 + id; break; }
        id -= cnt;
    }
    int rowBase = bi << 6;

    int t = threadIdx.x, lane = t & 63, w = t >> 6;
    int wr = (w & 1) << 5, wc = (w >> 1) << 5;   // 2x2 waves of 32x32
    int fr = lane & 15, kg = lane >> 4, lo = lane << 4;

    const char* base = reinterpret_cast<const char*>(ebs);

    // A fragments in registers for the whole block (8 coalesced 1KB loads)
    short8 A[2][4];
    int aT = (rowBase >> 4) + (wr >> 4);
    #pragma unroll
    for (int m = 0; m < 2; ++m)
        #pragma unroll
        for (int kk = 0; kk < 4; ++kk)
            A[m][kk] = *reinterpret_cast<const short8*>(
                           base + (size_t)(aT + m) * 4096 + kk * 1024 + lo);

    // block-invariant row norms / labels
    float4 sqi[2]; int4 labi[2];
    #pragma unroll
    for (int m = 0; m < 2; ++m) {
        int irb = rowBase + wr + m * 16 + kg * 4;
        sqi[m]  = *reinterpret_cast<const float4*>(sq + irb);
        labi[m] = *reinterpret_cast<const int4*>(labels + irb);
    }

    float l0 = 0.0f, l1 = 0.0f, l2 = 0.0f, l3 = 0.0f;
    int c8  = c << 3;
    int jt0 = bi > c8 ? bi : c8;
    int jt1 = c8 + 8;

    short8 Bb[2][2][4];        // [buf][colSubtile][kk]
    float  sqj[2][2];
    int    labj[2][2];

    // prefetch tile JT's B fragments + column norms/labels into buffer BUF
    #define LOADT(BUF, JT)                                                     \
    {                                                                          \
        const char* gB = base + ((size_t)((JT) << 2) + (wc >> 4)) * 4096;      \
        _Pragma("unroll")                                                      \
        for (int kk = 0; kk < 4; ++kk) {                                       \
            Bb[BUF][0][kk] = *reinterpret_cast<const short8*>(gB        + kk * 1024 + lo); \
            Bb[BUF][1][kk] = *reinterpret_cast<const short8*>(gB + 4096 + kk * 1024 + lo); \
        }                                                                      \
        int colBase = (JT) << 6;                                               \
        sqj[BUF][0]  = sq[colBase + wc + fr];                                  \
        sqj[BUF][1]  = sq[colBase + wc + 16 + fr];                             \
        labj[BUF][0] = labels[colBase + wc + fr];                              \
        labj[BUF][1] = labels[colBase + wc + 16 + fr];                         \
    }

    #define EPI(BUF, PRED)                                                     \
    {                                                                          \
        _Pragma("unroll")                                                      \
        for (int m = 0; m < 2; ++m) {                                          \
            int irb = wr + m * 16 + kg * 4;                                    \
            _Pragma("unroll")                                                  \
            for (int nn = 0; nn < 2; ++nn) {                                   \
                float sj = sqj[BUF][nn];                                       \
                int   lj = labj[BUF][nn];                                      \
                int   jc = wc + nn * 16 + fr; (void)jc;                        \
                _Pragma("unroll")                                              \
                for (int r4 = 0; r4 < 4; ++r4) {                               \
                    int ir = irb + r4; (void)ir;                               \
                    if (PRED) {                                                \
                        float si = (r4 == 0) ? sqi[m].x : (r4 == 1) ? sqi[m].y \
                                 : (r4 == 2) ? sqi[m].z : sqi[m].w;            \
                        int   li = (r4 == 0) ? labi[m].x : (r4 == 1) ? labi[m].y \
                                 : (r4 == 2) ? labi[m].z : labi[m].w;          \
                        float d2   = fmaf(-2.0f, acc[m][nn][r4], si + sj);     \
                        float dist = __builtin_amdgcn_sqrtf(fmaxf(d2, 0.0f));  \
                        float ds   = __builtin_amdgcn_sqrtf(dist + 1e-7f);     \
                        float v    = (li == lj) ? ds : fmaxf(1.0f - ds, 0.0f); \
                        if      (r4 == 0) l0 += v;                             \
                        else if (r4 == 1) l1 += v;                             \
                        else if (r4 == 2) l2 += v;                             \
                        else              l3 += v;                             \
                    }                                                          \
                }                                                              \
            }                                                                  \
        }                                                                      \
    }

    #define COMPUTE(BUF, JT)                                                   \
    {                                                                          \
        f32x4 acc[2][2];                                                       \
        const f32x4 zero = {0.0f, 0.0f, 0.0f, 0.0f};                           \
        acc[0][0] = zero; acc[0][1] = zero; acc[1][0] = zero; acc[1][1] = zero; \
        _Pragma("unroll")                                                      \
        for (int kk = 0; kk < 4; ++kk) {                                       \
            acc[0][0] = __builtin_amdgcn_mfma_f32_16x16x32_bf16(A[0][kk], Bb[BUF][0][kk], acc[0][0], 0, 0, 0); \
            acc[0][1] = __builtin_amdgcn_mfma_f32_16x16x32_bf16(A[0][kk], Bb[BUF][1][kk], acc[0][1], 0, 0, 0); \
            acc[1][0] = __builtin_amdgcn_mfma_f32_16x16x32_bf16(A[1][kk], Bb[BUF][0][kk], acc[1][0], 0, 0, 0); \
            acc[1][1] = __builtin_amdgcn_mfma_f32_16x16x32_bf16(A[1][kk], Bb[BUF][1][kk], acc[1][1], 0, 0, 0); \
        }                                                                      \
        if ((JT) + 1 < jt1) LOADT(1 - (BUF), (JT) + 1);                        \
        if ((JT) > bi) EPI(BUF, true)                                          \
        else           EPI(BUF, jc > ir)                                       \
    }

    int jt = jt0;
    LOADT(0, jt)
    for (;;) {
        COMPUTE(0, jt)
        ++jt; if (jt >= jt1) break;
        COMPUTE(1, jt)
        ++jt; if (jt >= jt1) break;
    }
    #undef COMPUTE
    #undef EPI
    #undef LOADT

    float local = (l0 + l1) + (l2 + l3);
    #pragma unroll
    for (int off = 32; off > 0; off >>= 1) local += __shfl_down(local, off);
    if (lane == 0) wsum[w] = local;
    __syncthreads();
    if (t == 0) {
        atomicAdd(accum, (wsum[0] + wsum[1]) + (wsum[2] + wsum[3]));
        __threadfence();
        unsigned int old = atomicAdd(counter, 1u);
        if (old == (unsigned int)(nBlocks - 1)) {
            float tot = atomicAdd(accum, 0.0f);   // coherent read of final sum
            out[0] = tot * inv_pairs;
        }
    }
}

extern "C" void kernel_launch(void* const* d_in, const int* in_sizes, int n_in,
                              void* d_out, int out_size, void* d_ws, size_t ws_size,
                              hipStream_t stream) {
    const float* emb   = (const float*)d_in[0];
    const int*  labels = (const int*)d_in[1];
    int n   = in_sizes[1];         // 8192
    int nb  = n >> 6;              // 64-row bands -> 128
    int nch = nb >> 3;             // 8-tile chunks -> 16

    float*          accum   = (float*)d_ws;
    unsigned int*   counter = (unsigned int*)((char*)d_ws + 8);
    float*          sq      = (float*)((char*)d_ws + 256);
    unsigned short* ebs     = (unsigned short*)((char*)d_ws + 65536);

    prep_kernel<<<n / 16, 256, 0, stream>>>(emb, ebs, sq, accum, counter, n);

    int nBlocks = nb * nch - 8 * (nch * (nch - 1) / 2);   // 1088 for n=8192
    float inv_pairs = (float)(2.0 / ((double)n * (double)(n - 1)));
    loss_kernel<<<nBlocks, 256, 0, stream>>>(ebs, labels, sq, accum, counter,
                                             (float*)d_out, inv_pairs,
                                             nb, nch, nBlocks);
}

// Round 11
// 50.252 us; speedup vs baseline: 2.7041x; 2.7041x over previous
//
#include <hip/hip_runtime.h>
#include <hip/hip_bf16.h>
#include <stdint.h>

typedef __attribute__((ext_vector_type(8))) short short8;
typedef __attribute__((ext_vector_type(4))) float f32x4;

__device__ __forceinline__ unsigned int f2bf(float f) {
    unsigned int u = __float_as_uint(f);
    return (u + 0x7fffu + ((u >> 16) & 1u)) >> 16;   // RNE fp32 -> bf16
}

// ---- kernel 1: fp32 -> bf16 in FRAGMENT-NATIVE layout + row squared norms ----
// Element (row,k) at byte (row>>4)*4096 + (k>>3)*256 + (row&15)*16 + (k&7)*2.
// A 64-row tile is a contiguous 16 KB block. Also zeroes accum + counter.
__global__ void prep_kernel(const float* __restrict__ emb,
                            unsigned short* __restrict__ ebs,
                            float* __restrict__ sq,
                            float* __restrict__ accum,
                            unsigned int* __restrict__ counter, int n) {
    int t = threadIdx.x;
    if (blockIdx.x == 0 && t == 0) { accum[0] = 0.0f; counter[0] = 0u; }
    int row = blockIdx.x * 16 + (t >> 4);
    int c   = t & 15;                       // k-chunk (8 elems / 16B)
    if (row >= n) return;
    const float* src = emb + (size_t)row * 128 + c * 8;
    float4 f0 = *reinterpret_cast<const float4*>(src);
    float4 f1 = *reinterpret_cast<const float4*>(src + 4);
    uint4 wv;
    wv.x = f2bf(f0.x) | (f2bf(f0.y) << 16);
    wv.y = f2bf(f0.z) | (f2bf(f0.w) << 16);
    wv.z = f2bf(f1.x) | (f2bf(f1.y) << 16);
    wv.w = f2bf(f1.z) | (f2bf(f1.w) << 16);
    size_t byte = (size_t)(row >> 4) * 4096 + c * 256 + (row & 15) * 16;
    *reinterpret_cast<uint4*>(reinterpret_cast<char*>(ebs) + byte) = wv;
    float p = f0.x*f0.x + f0.y*f0.y + f0.z*f0.z + f0.w*f0.w
            + f1.x*f1.x + f1.y*f1.y + f1.z*f1.z + f1.w*f1.w;
    #pragma unroll
    for (int off = 1; off < 16; off <<= 1) p += __shfl_xor(p, off);
    if (c == 0) sq[row] = p;
}

// ---- kernel 2: A-in-regs, B LDS-double-buffered via async global_load_lds ----
// Block = (64-row band bi, chunk c of 8 col-tiles of 64). 4 waves of 32x32.
// 2-phase pipeline: STAGE(next tile) issued before COMPUTE(current tile).
__launch_bounds__(256, 4)
__global__ void loss_kernel(const unsigned short* __restrict__ ebs,
                            const int* __restrict__ labels,
                            const float* __restrict__ sq,
                            float* __restrict__ accum,
                            unsigned int* __restrict__ counter,
                            float* __restrict__ out, float inv_pairs,
                            int nb, int nch, int nBlocks) {
    __shared__ __align__(16) char Bs0[16384];
    __shared__ __align__(16) char Bs1[16384];
    __shared__ float wsum[4];

    // blockIdx -> (bi, c): only chunks containing tiles jt >= bi
    int id = blockIdx.x, bi = 0, c = 0;
    for (bi = 0; bi < nb; ++bi) {
        int c0  = bi >> 3;
        int cnt = nch - c0;
        if (id < cnt) { c = c0 + id; break; }
        id -= cnt;
    }
    int rowBase = bi << 6;

    int t = threadIdx.x, lane = t & 63, w = t >> 6;
    int wr = (w & 1) << 5, wc = (w >> 1) << 5;   // 2x2 waves of 32x32
    int fr = lane & 15, kg = lane >> 4, lo = lane << 4;

    const char* base = reinterpret_cast<const char*>(ebs);

    // A fragments in registers for the whole block (8 coalesced 1KB loads)
    short8 A[2][4];
    int aT = (rowBase >> 4) + (wr >> 4);
    #pragma unroll
    for (int m = 0; m < 2; ++m)
        #pragma unroll
        for (int kk = 0; kk < 4; ++kk)
            A[m][kk] = *reinterpret_cast<const short8*>(
                           base + (size_t)(aT + m) * 4096 + kk * 1024 + lo);

    // block-invariant row norms / labels
    float4 sqi[2]; int4 labi[2];
    #pragma unroll
    for (int m = 0; m < 2; ++m) {
        int irb = rowBase + wr + m * 16 + kg * 4;
        sqi[m]  = *reinterpret_cast<const float4*>(sq + irb);
        labi[m] = *reinterpret_cast<const int4*>(labels + irb);
    }

    float l0 = 0.0f, l1 = 0.0f, l2 = 0.0f, l3 = 0.0f;
    int c8  = c << 3;
    int jt0 = bi > c8 ? bi : c8;
    int jt1 = c8 + 8;
    int thrOff = t << 4;

    // async-stage 16 KB tile JT (contiguous in frag-native layout) into BUFP
    #define STAGE(BUFP, JT)                                                    \
    {                                                                          \
        const char* gB = base + (size_t)(JT) * 16384;                          \
        _Pragma("unroll")                                                      \
        for (int it = 0; it < 4; ++it) {                                       \
            int off = (it << 12) + thrOff;                                     \
            __builtin_amdgcn_global_load_lds(                                  \
                (const __attribute__((address_space(1))) void*)(gB + off),     \
                (__attribute__((address_space(3))) void*)((BUFP) + off), 16, 0, 0); \
        }                                                                      \
    }

    #define EPI(PRED)                                                          \
    {                                                                          \
        _Pragma("unroll")                                                      \
        for (int m = 0; m < 2; ++m) {                                          \
            int irb = wr + m * 16 + kg * 4;                                    \
            _Pragma("unroll")                                                  \
            for (int nn = 0; nn < 2; ++nn) {                                   \
                float sj = nn ? sqj1 : sqj0;                                   \
                int   lj = nn ? labj1 : labj0;                                 \
                int   jc = wc + nn * 16 + fr; (void)jc;                        \
                _Pragma("unroll")                                              \
                for (int r4 = 0; r4 < 4; ++r4) {                               \
                    int ir = irb + r4; (void)ir;                               \
                    if (PRED) {                                                \
                        float si = (r4 == 0) ? sqi[m].x : (r4 == 1) ? sqi[m].y \
                                 : (r4 == 2) ? sqi[m].z : sqi[m].w;            \
                        int   li = (r4 == 0) ? labi[m].x : (r4 == 1) ? labi[m].y \
                                 : (r4 == 2) ? labi[m].z : labi[m].w;          \
                        float d2   = fmaf(-2.0f, acc[m][nn][r4], si + sj);     \
                        float dist = __builtin_amdgcn_sqrtf(fmaxf(d2, 0.0f));  \
                        float ds   = __builtin_amdgcn_sqrtf(dist + 1e-7f);     \
                        float v    = (li == lj) ? ds : fmaxf(1.0f - ds, 0.0f); \
                        if      (r4 == 0) l0 += v;                             \
                        else if (r4 == 1) l1 += v;                             \
                        else if (r4 == 2) l2 += v;                             \
                        else              l3 += v;                             \
                    }                                                          \
                }                                                              \
            }                                                                  \
        }                                                                      \
    }

    #define COMPUTE(BUFP, JT)                                                  \
    {                                                                          \
        const char* Bp = (BUFP) + (wc >> 4) * 4096;                            \
        f32x4 acc[2][2];                                                       \
        const f32x4 zero = {0.0f, 0.0f, 0.0f, 0.0f};                           \
        acc[0][0] = zero; acc[0][1] = zero; acc[1][0] = zero; acc[1][1] = zero; \
        _Pragma("unroll")                                                      \
        for (int kk = 0; kk < 4; ++kk) {                                       \
            short8 b0 = *reinterpret_cast<const short8*>(Bp        + kk * 1024 + lo); \
            short8 b1 = *reinterpret_cast<const short8*>(Bp + 4096 + kk * 1024 + lo); \
            acc[0][0] = __builtin_amdgcn_mfma_f32_16x16x32_bf16(A[0][kk], b0, acc[0][0], 0, 0, 0); \
            acc[0][1] = __builtin_amdgcn_mfma_f32_16x16x32_bf16(A[0][kk], b1, acc[0][1], 0, 0, 0); \
            acc[1][0] = __builtin_amdgcn_mfma_f32_16x16x32_bf16(A[1][kk], b0, acc[1][0], 0, 0, 0); \
            acc[1][1] = __builtin_amdgcn_mfma_f32_16x16x32_bf16(A[1][kk], b1, acc[1][1], 0, 0, 0); \
        }                                                                      \
        int colBase = (JT) << 6;                                               \
        float sqj0  = sq[colBase + wc + fr];                                   \
        float sqj1  = sq[colBase + wc + 16 + fr];                              \
        int   labj0 = labels[colBase + wc + fr];                               \
        int   labj1 = labels[colBase + wc + 16 + fr];                          \
        if ((JT) > bi) EPI(true)                                               \
        else           EPI(jc > ir)                                            \
    }

    int jt = jt0;
    STAGE(Bs0, jt)
    __syncthreads();                          // buf0 ready
    for (;;) {
        if (jt + 1 < jt1) STAGE(Bs1, jt + 1)  // issue next before compute
        COMPUTE(Bs0, jt)
        __syncthreads();                      // buf1 ready, buf0 free
        ++jt; if (jt >= jt1) break;
        if (jt + 1 < jt1) STAGE(Bs0, jt + 1)
        COMPUTE(Bs1, jt)
        __syncthreads();
        ++jt; if (jt >= jt1) break;
    }
    #undef COMPUTE
    #undef EPI
    #undef STAGE

    float local = (l0 + l1) + (l2 + l3);
    #pragma unroll
    for (int off = 32; off > 0; off >>= 1) local += __shfl_down(local, off);
    if (lane == 0) wsum[w] = local;
    __syncthreads();
    if (t == 0) {
        atomicAdd(accum, (wsum[0] + wsum[1]) + (wsum[2] + wsum[3]));
        __threadfence();
        unsigned int old = atomicAdd(counter, 1u);
        if (old == (unsigned int)(nBlocks - 1)) {
            float tot = atomicAdd(accum, 0.0f);   // coherent read of final sum
            out[0] = tot * inv_pairs;
        }
    }
}

extern "C" void kernel_launch(void* const* d_in, const int* in_sizes, int n_in,
                              void* d_out, int out_size, void* d_ws, size_t ws_size,
                              hipStream_t stream) {
    const float* emb   = (const float*)d_in[0];
    const int*  labels = (const int*)d_in[1];
    int n   = in_sizes[1];         // 8192
    int nb  = n >> 6;              // 64-row bands -> 128
    int nch = nb >> 3;             // 8-tile chunks -> 16

    float*          accum   = (float*)d_ws;
    unsigned int*   counter = (unsigned int*)((char*)d_ws + 8);
    float*          sq      = (float*)((char*)d_ws + 256);
    unsigned short* ebs     = (unsigned short*)((char*)d_ws + 65536);

    prep_kernel<<<n / 16, 256, 0, stream>>>(emb, ebs, sq, accum, counter, n);

    int nBlocks = nb * nch - 8 * (nch * (nch - 1) / 2);   // 1088 for n=8192
    float inv_pairs = (float)(2.0 / ((double)n * (double)(n - 1)));
    loss_kernel<<<nBlocks, 256, 0, stream>>>(ebs, labels, sq, accum, counter,
                                             (float*)d_out, inv_pairs,
                                             nb, nch, nBlocks);
}